// Round 6
// baseline (116.909 us; speedup 1.0000x reference)
//
#include <hip/hip_runtime.h>

#define IMG_H 512
#define IMG_W 512
#define N_IMG 32
#define NPIX  (32.0f * 512.0f * 512.0f)
#define STRIP 520                    // 4 zero-pad + 512 + 4 zero-pad

// Load 8 consecutive cols of I and normalized T from row r (zeros outside image).
__device__ __forceinline__ void load_row8(const float* __restrict__ ip,
                                          const float* __restrict__ tp,
                                          int r, int c0, float* I, float* T) {
    if ((unsigned)r < (unsigned)IMG_H) {           // wave-uniform branch
        const float* irow = ip + (ptrdiff_t)r * IMG_W + c0;
        const float* trow = tp + (ptrdiff_t)r * IMG_W + c0;
        float4 a = *(const float4*)(irow);
        float4 b = *(const float4*)(irow + 4);
        float4 c = *(const float4*)(trow);
        float4 d = *(const float4*)(trow + 4);
        I[0]=a.x; I[1]=a.y; I[2]=a.z; I[3]=a.w;
        I[4]=b.x; I[5]=b.y; I[6]=b.z; I[7]=b.w;
        T[0]=fmaf(c.x,0.5f,0.5f); T[1]=fmaf(c.y,0.5f,0.5f);
        T[2]=fmaf(c.z,0.5f,0.5f); T[3]=fmaf(c.w,0.5f,0.5f);
        T[4]=fmaf(d.x,0.5f,0.5f); T[5]=fmaf(d.y,0.5f,0.5f);
        T[6]=fmaf(d.z,0.5f,0.5f); T[7]=fmaf(d.w,0.5f,0.5f);
    } else {
        #pragma unroll
        for (int j = 0; j < 8; ++j) { I[j] = 0.0f; T[j] = 0.0f; }
    }
}

__device__ __forceinline__ void accum(float V[5][8], const float* I, const float* T) {
    #pragma unroll
    for (int j = 0; j < 8; ++j) {
        V[0][j] += I[j];
        V[1][j] += T[j];
        V[2][j] = fmaf(I[j], I[j], V[2][j]);
        V[3][j] = fmaf(T[j], T[j], V[3][j]);
        V[4][j] = fmaf(I[j], T[j], V[4][j]);
    }
}

// 9-tap horizontal sliding sums: L = cols c0-4..c0-1, o = own 8, R = cols c0+8..c0+11.
__device__ __forceinline__ void hsum8(const float4 L, const float* o, const float4 R,
                                      float* h) {
    float s = ((L.x + L.y) + (L.z + L.w)) + ((o[0] + o[1]) + (o[2] + o[3])) + o[4];
    h[0] = s;
    s += o[5] - L.x;  h[1] = s;
    s += o[6] - L.y;  h[2] = s;
    s += o[7] - L.z;  h[3] = s;
    s += R.x  - L.w;  h[4] = s;
    s += R.y  - o[0]; h[5] = s;
    s += R.z  - o[1]; h[6] = s;
    s += R.w  - o[2]; h[7] = s;
}

__device__ __forceinline__ float cc_of(float sI, float sT, float sII, float sTT, float sIT) {
    const float inv81 = 1.0f / 81.0f;
    float u     = sI * inv81;
    float w     = sT * inv81;
    float cross = fmaf(-u, sT, sIT);
    float iv    = fmaf(-u, sI, sII);
    float tv    = fmaf(-w, sT, sTT);
    float den   = fmaf(tv, iv, 1e-5f);
    return cross * cross * __builtin_amdgcn_rcpf(den);
}

// H-phase for one output row: single reused wave-private strip, wave-local ordering only.
__device__ __forceinline__ float hphase_cc(float* sp, int c0, const float V[5][8]) {
    float h[5][8];
    #pragma unroll
    for (int a = 0; a < 5; ++a) {
        float4* wp = (float4*)(sp + 4 + c0);
        wp[0] = make_float4(V[a][0], V[a][1], V[a][2], V[a][3]);
        wp[1] = make_float4(V[a][4], V[a][5], V[a][6], V[a][7]);
        __builtin_amdgcn_wave_barrier();          // same-wave DS pipe is in-order
        float4 L = *(const float4*)(sp + c0);
        float4 R = *(const float4*)(sp + c0 + 12);
        __builtin_amdgcn_wave_barrier();          // keep next array's write after these reads
        hsum8(L, &V[a][0], R, h[a]);
    }
    float s = 0.0f;
    #pragma unroll
    for (int j = 0; j < 8; ++j)
        s += cc_of(h[0][j], h[1][j], h[2][j], h[3][j], h[4][j]);
    return s;
}

__global__ __launch_bounds__(256)
void cc_loss_kernel(const float* __restrict__ in, const float* __restrict__ tg,
                    float* __restrict__ out) {
    __shared__ __align__(16) float strip[4][STRIP];   // one 2.08 KB strip per wave
    __shared__ float red[4];

    const int t    = threadIdx.x;
    const int w    = t >> 6;
    const int lane = t & 63;

    // XCD-locality swizzle: XCD (blockIdx%8) works images 4*slab..4*slab+3.
    const int slab = blockIdx.x & 7;
    const int idx  = blockIdx.x >> 3;
    const int gtask = slab * 1024 + idx * 4 + w;      // 0..8191 wave tasks
    const int img   = gtask >> 8;                     // 256 row-pairs per image
    const int pair  = gtask & 255;
    const int rA    = pair * 2;                       // output rows rA, rA+1
    const int c0    = lane * 8;                       // own cols c0..c0+7

    const size_t base = (size_t)img * (IMG_H * IMG_W);
    const float* ip = in + base;
    const float* tp = tg + base;
    float* sp = strip[w];

    if (lane < 8) sp[(lane & 3) + ((lane & 4) ? 516 : 0)] = 0.0f;  // zero halo pads once
    __builtin_amdgcn_wave_barrier();

    float V[5][8] = {{0.f}};                          // I,T,II,TT,IT vertical 9-sums (row A)
    float loI[8], loT[8], hiI[8], hiT[8];

    // window A = rows rA-4 .. rA+4 ; keep the bottom row (rA-4) for the slide to B.
    load_row8(ip, tp, rA - 4, c0, loI, loT);
    accum(V, loI, loT);
    #pragma unroll
    for (int k = -3; k <= 4; ++k) {
        float I[8], T[8];
        load_row8(ip, tp, rA + k, c0, I, T);
        accum(V, I, T);
    }
    load_row8(ip, tp, rA + 5, c0, hiI, hiT);          // row entering window B (in flight early)

    float acc = hphase_cc(sp, c0, V);                 // output row rA

    // slide window: B = A - row(rA-4) + row(rA+5)
    #pragma unroll
    for (int j = 0; j < 8; ++j) {
        float dI = hiI[j] - loI[j], aI = hiI[j] + loI[j];
        float dT = hiT[j] - loT[j], aT = hiT[j] + loT[j];
        V[0][j] += dI;
        V[1][j] += dT;
        V[2][j] = fmaf(dI, aI, V[2][j]);
        V[3][j] = fmaf(dT, aT, V[3][j]);
        V[4][j] = fmaf(hiI[j], hiT[j], V[4][j] - loI[j] * loT[j]);
    }
    acc += hphase_cc(sp, c0, V);                      // output row rA+1

    // ---- reduction: wave shuffle, one block barrier, one atomic ----
    #pragma unroll
    for (int off = 32; off > 0; off >>= 1) acc += __shfl_down(acc, off);
    if (lane == 0) red[w] = acc;
    __syncthreads();
    if (t == 0)
        atomicAdd(out, (red[0] + red[1] + red[2] + red[3]) * (-1.0f / NPIX));
}

extern "C" void kernel_launch(void* const* d_in, const int* in_sizes, int n_in,
                              void* d_out, int out_size, void* d_ws, size_t ws_size,
                              hipStream_t stream) {
    const float* in = (const float*)d_in[0];
    const float* tg = (const float*)d_in[1];
    float* out = (float*)d_out;

    hipMemsetAsync(out, 0, sizeof(float), stream);
    dim3 grid(2048);                                  // 8192 wave-tasks / 4 waves per block
    cc_loss_kernel<<<grid, 256, 0, stream>>>(in, tg, out);
}

// Round 7
// 112.212 us; speedup vs baseline: 1.0419x; 1.0419x over previous
//
#include <hip/hip_runtime.h>

#define IMG_H 512
#define IMG_W 512
#define N_IMG 32
#define NPIX  (32.0f * 512.0f * 512.0f)

// Load 8 consecutive cols of I and normalized T from row r (zeros outside image).
__device__ __forceinline__ void load_row8(const float* __restrict__ ip,
                                          const float* __restrict__ tp,
                                          int r, int c0, float* I, float* T) {
    if ((unsigned)r < (unsigned)IMG_H) {           // wave-uniform branch
        const float* irow = ip + (ptrdiff_t)r * IMG_W + c0;
        const float* trow = tp + (ptrdiff_t)r * IMG_W + c0;
        float4 a = *(const float4*)(irow);
        float4 b = *(const float4*)(irow + 4);
        float4 c = *(const float4*)(trow);
        float4 d = *(const float4*)(trow + 4);
        I[0]=a.x; I[1]=a.y; I[2]=a.z; I[3]=a.w;
        I[4]=b.x; I[5]=b.y; I[6]=b.z; I[7]=b.w;
        T[0]=fmaf(c.x,0.5f,0.5f); T[1]=fmaf(c.y,0.5f,0.5f);
        T[2]=fmaf(c.z,0.5f,0.5f); T[3]=fmaf(c.w,0.5f,0.5f);
        T[4]=fmaf(d.x,0.5f,0.5f); T[5]=fmaf(d.y,0.5f,0.5f);
        T[6]=fmaf(d.z,0.5f,0.5f); T[7]=fmaf(d.w,0.5f,0.5f);
    } else {
        #pragma unroll
        for (int j = 0; j < 8; ++j) { I[j] = 0.0f; T[j] = 0.0f; }
    }
}

__device__ __forceinline__ void accum(float V[5][8], const float* I, const float* T) {
    #pragma unroll
    for (int j = 0; j < 8; ++j) {
        V[0][j] += I[j];
        V[1][j] += T[j];
        V[2][j] = fmaf(I[j], I[j], V[2][j]);
        V[3][j] = fmaf(T[j], T[j], V[3][j]);
        V[4][j] = fmaf(I[j], T[j], V[4][j]);
    }
}

__device__ __forceinline__ void slide(float V[5][8], const float* hI, const float* hT,
                                      const float* lI, const float* lT) {
    #pragma unroll
    for (int j = 0; j < 8; ++j) {
        float dI = hI[j] - lI[j], aI = hI[j] + lI[j];
        float dT = hT[j] - lT[j], aT = hT[j] + lT[j];
        V[0][j] += dI;
        V[1][j] += dT;
        V[2][j] = fmaf(dI, aI, V[2][j]);
        V[3][j] = fmaf(dT, aT, V[3][j]);
        V[4][j] = fmaf(hI[j], hT[j], V[4][j] - lI[j] * lT[j]);
    }
}

__device__ __forceinline__ float cc_of(float sI, float sT, float sII, float sTT, float sIT) {
    const float inv81 = 1.0f / 81.0f;
    float u     = sI * inv81;
    float w     = sT * inv81;
    float cross = fmaf(-u, sT, sIT);
    float iv    = fmaf(-u, sI, sII);
    float tv    = fmaf(-w, sT, sTT);
    float den   = fmaf(tv, iv, 1e-5f);
    return cross * cross * __builtin_amdgcn_rcpf(den);
}

// One output row: halo via wave shuffles (ds_bpermute), zero LDS, no barriers.
__device__ __forceinline__ float hphase_cc(const float V[5][8], int lane) {
    float h[5][8];
    const bool l0 = (lane == 0), l63 = (lane == 63);
    #pragma unroll
    for (int a = 0; a < 5; ++a) {
        const float* o = V[a];
        float L0 = __shfl_up(o[4], 1);
        float L1 = __shfl_up(o[5], 1);
        float L2 = __shfl_up(o[6], 1);
        float L3 = __shfl_up(o[7], 1);
        float R0 = __shfl_down(o[0], 1);
        float R1 = __shfl_down(o[1], 1);
        float R2 = __shfl_down(o[2], 1);
        float R3 = __shfl_down(o[3], 1);
        if (l0)  { L0 = 0.f; L1 = 0.f; L2 = 0.f; L3 = 0.f; }   // image left pad
        if (l63) { R0 = 0.f; R1 = 0.f; R2 = 0.f; R3 = 0.f; }   // image right pad
        float s = ((L0 + L1) + (L2 + L3)) + ((o[0] + o[1]) + (o[2] + o[3])) + o[4];
        h[a][0] = s;
        s += o[5] - L0;  h[a][1] = s;
        s += o[6] - L1;  h[a][2] = s;
        s += o[7] - L2;  h[a][3] = s;
        s += R0   - L3;  h[a][4] = s;
        s += R1   - o[0]; h[a][5] = s;
        s += R2   - o[1]; h[a][6] = s;
        s += R3   - o[2]; h[a][7] = s;
    }
    float acc = 0.0f;
    #pragma unroll
    for (int j = 0; j < 8; ++j)
        acc += cc_of(h[0][j], h[1][j], h[2][j], h[3][j], h[4][j]);
    return acc;
}

__global__ __launch_bounds__(256)
void cc_loss_kernel(const float* __restrict__ in, const float* __restrict__ tg,
                    float* __restrict__ out) {
    __shared__ float red[4];

    const int t    = threadIdx.x;
    const int w    = t >> 6;
    const int lane = t & 63;

    // XCD-locality swizzle: XCD (blockIdx%8) gets a 4-image slab.
    const int slab = blockIdx.x & 7;
    const int idx  = blockIdx.x >> 3;                 // 0..127
    const int gtask = slab * 512 + idx * 4 + w;       // 0..4095 wave tasks
    const int img   = gtask >> 7;                     // 128 row-quads per image
    const int quad  = gtask & 127;
    const int rA    = quad * 4;                       // output rows rA..rA+3
    const int c0    = lane * 8;

    const size_t base = (size_t)img * (IMG_H * IMG_W);
    const float* ip = in + base;
    const float* tp = tg + base;

    float V[5][8] = {{0.f}};
    float acc = 0.0f;

    {   // warm-up: rows rA-4 .. rA+3, then lead row rA+4 completes window A
        float I[8], T[8];
        #pragma unroll
        for (int k = 0; k < 9; ++k) {
            load_row8(ip, tp, rA - 4 + k, c0, I, T);
            accum(V, I, T);
        }
    }

    float nLI[8], nLT[8], nQI[8], nQT[8];
    #pragma unroll
    for (int j = 1; j <= 3; ++j) {
        load_row8(ip, tp, rA + 4 + j, c0, nLI, nLT);  // entering row (prefetch)
        load_row8(ip, tp, rA - 5 + j, c0, nQI, nQT);  // leaving row (L2-warm re-read)
        acc += hphase_cc(V, lane);                    // output row rA+j-1
        slide(V, nLI, nLT, nQI, nQT);
    }
    acc += hphase_cc(V, lane);                        // output row rA+3

    // ---- reduction: wave shuffle, one block barrier, one atomic ----
    #pragma unroll
    for (int off = 32; off > 0; off >>= 1) acc += __shfl_down(acc, off);
    if (lane == 0) red[w] = acc;
    __syncthreads();
    if (t == 0)
        atomicAdd(out, (red[0] + red[1] + red[2] + red[3]) * (-1.0f / NPIX));
}

extern "C" void kernel_launch(void* const* d_in, const int* in_sizes, int n_in,
                              void* d_out, int out_size, void* d_ws, size_t ws_size,
                              hipStream_t stream) {
    const float* in = (const float*)d_in[0];
    const float* tg = (const float*)d_in[1];
    float* out = (float*)d_out;

    hipMemsetAsync(out, 0, sizeof(float), stream);
    dim3 grid(1024);                                  // 4096 wave-tasks / 4 waves per block
    cc_loss_kernel<<<grid, 256, 0, stream>>>(in, tg, out);
}